// Round 3
// baseline (285.715 us; speedup 1.0000x reference)
//
#include <hip/hip_runtime.h>
#include <hip/hip_bf16.h>

typedef float f32x4 __attribute__((ext_vector_type(4)));
typedef short s16x8 __attribute__((ext_vector_type(8)));

#define NROWS 8192
#define MCOLS 8192
#define DIM   128
#define BI    32
#define NTILE 256   // MCOLS / 32

// ---- prep: per-row norm + scale + bf16 convert (row-major out) ----
__global__ void prep_scale_rows(const float* __restrict__ x,
                                const float* __restrict__ beta,
                                __hip_bfloat16* __restrict__ outbf) {
    int row = blockIdx.x * 4 + (threadIdx.x >> 6);
    int l = threadIdx.x & 63;
    const float* xr = x + (size_t)row * DIM;
    float x0 = xr[l], x1 = xr[l + 64];
    float ss = x0 * x0 + x1 * x1;
#pragma unroll
    for (int off = 32; off >= 1; off >>= 1) ss += __shfl_xor(ss, off);
    float s = (beta ? beta[0] : 1.0f) / sqrtf(ss);
    __hip_bfloat16* o = outbf + (size_t)row * DIM;
    o[l]      = __float2bfloat16(x0 * s);
    o[l + 64] = __float2bfloat16(x1 * s);
}

// ---- prep: transpose xj -> Vt[d][j] bf16 (raw values) ----
__global__ void prep_vt(const float* __restrict__ xj, __hip_bfloat16* __restrict__ vt) {
    __shared__ float tile[64][65];
    int j0 = blockIdx.x * 64;
    int d0 = blockIdx.y * 64;
    int t = threadIdx.x; // 256
#pragma unroll
    for (int c = 0; c < 16; ++c) {
        int idx = t + 256 * c;
        int jr = idx >> 6, dc = idx & 63;
        tile[jr][dc] = xj[(size_t)(j0 + jr) * DIM + d0 + dc];
    }
    __syncthreads();
#pragma unroll
    for (int c = 0; c < 16; ++c) {
        int idx = t + 256 * c;
        int dr = idx >> 6, jc = idx & 63;
        vt[(size_t)(d0 + dr) * MCOLS + j0 + jc] = __float2bfloat16(tile[jc][dr]);
    }
}

// ---- flash attention, no max-tracking (scores bounded by |beta| <= 1),
//      barrier-free main loop, adj streamed nontemporal, K/V from L2 ----
__global__ __launch_bounds__(1024, 4) void flash3(const __hip_bfloat16* __restrict__ Qbf,
                                                  const __hip_bfloat16* __restrict__ Kbf,
                                                  const __hip_bfloat16* __restrict__ Vt,
                                                  const int* __restrict__ adj,
                                                  float* __restrict__ out) {
    __shared__ char smem[66048];
    __hip_bfloat16* Plds  = (__hip_bfloat16*)smem;   // [16 waves][16][40] = 20.5 KiB
    float*          Opart = (float*)smem;            // epilogue: [8][16][128] = 64 KiB (reuse)
    float*          Lpart = (float*)(smem + 65536);  // epilogue: [8][16]

    const int tid  = threadIdx.x;
    const int w    = tid >> 6;
    const int lane = tid & 63;
    const int g    = lane >> 4;
    const int ln   = lane & 15;
    const int wi   = w >> 3;   // 0..1 row group (16 rows each)
    const int wj   = w & 7;    // 0..7 j slice
    const int i0   = blockIdx.x * BI;
    const int ri0  = i0 + wi * 16;

    // Q fragments (A-operand): lane holds Q[ri0+ln][kt*32 + g*8 + e]
    s16x8 qf[4];
#pragma unroll
    for (int kt = 0; kt < 4; ++kt)
        qf[kt] = *(const s16x8*)(Qbf + (size_t)(ri0 + ln) * DIM + kt * 32 + g * 8);

    f32x4 zero = {0.f, 0.f, 0.f, 0.f};
    f32x4 acc[8];
#pragma unroll
    for (int dt = 0; dt < 8; ++dt) acc[dt] = zero;
    float lr[4] = {0.f, 0.f, 0.f, 0.f};

    __hip_bfloat16* pme = Plds + w * 640; // [16][40] bf16 per wave

    const int* arow = adj + (size_t)(ri0 + g * 4) * MCOLS + ln;

    // prologue: adj for first tile
    int amc[2][4];
    {
        const int jt = wj * 32;
#pragma unroll
        for (int jt2 = 0; jt2 < 2; ++jt2)
#pragma unroll
            for (int r = 0; r < 4; ++r)
                amc[jt2][r] = __builtin_nontemporal_load(arow + (size_t)r * MCOLS + jt + jt2 * 16);
    }

    for (int t = wj; t < NTILE; t += 8) {
        // prefetch next tile's adj (registers; hides HBM latency under compute)
        int amn[2][4];
        if (t + 8 < NTILE) {
            const int jtn = (t + 8) * 32;
#pragma unroll
            for (int jt2 = 0; jt2 < 2; ++jt2)
#pragma unroll
                for (int r = 0; r < 4; ++r)
                    amn[jt2][r] = __builtin_nontemporal_load(arow + (size_t)r * MCOLS + jtn + jt2 * 16);
        }
        const int jt = t * 32;

        // S = Q K^T (16 rows x 32 cols), K fragments straight from L2
        f32x4 s[2];
#pragma unroll
        for (int jt2 = 0; jt2 < 2; ++jt2) {
            s[jt2] = zero;
#pragma unroll
            for (int kt = 0; kt < 4; ++kt) {
                s16x8 kfrag = *(const s16x8*)(Kbf + (size_t)(jt + jt2 * 16 + ln) * DIM + kt * 32 + g * 8);
                s[jt2] = __builtin_amdgcn_mfma_f32_16x16x32_bf16(qf[kt], kfrag, s[jt2], 0, 0, 0);
            }
        }

        // softmax-lite: p = adj ? exp(s) : 0   (s in [-1,1], no overflow, no max)
#pragma unroll
        for (int r = 0; r < 4; ++r) {
            float p0 = amc[0][r] ? __expf(s[0][r]) : 0.f;
            float p1 = amc[1][r] ? __expf(s[1][r]) : 0.f;
            lr[r] += p0 + p1;
            pme[(g * 4 + r) * 40 + ln]      = __float2bfloat16(p0);
            pme[(g * 4 + r) * 40 + 16 + ln] = __float2bfloat16(p1);
        }

        // PV (same-wave LDS RAW; compiler inserts lgkmcnt wait)
        s16x8 pf = *(const s16x8*)(pme + ln * 40 + g * 8);
#pragma unroll
        for (int dt = 0; dt < 8; ++dt) {
            s16x8 vfrag = *(const s16x8*)(Vt + (size_t)(dt * 16 + ln) * MCOLS + jt + g * 8);
            acc[dt] = __builtin_amdgcn_mfma_f32_16x16x32_bf16(pf, vfrag, acc[dt], 0, 0, 0);
        }

#pragma unroll
        for (int jt2 = 0; jt2 < 2; ++jt2)
#pragma unroll
            for (int r = 0; r < 4; ++r) amc[jt2][r] = amn[jt2][r];
    }

    // finalize row sums (within 16-lane group)
#pragma unroll
    for (int r = 0; r < 4; ++r) {
        lr[r] += __shfl_xor(lr[r], 1);
        lr[r] += __shfl_xor(lr[r], 2);
        lr[r] += __shfl_xor(lr[r], 4);
        lr[r] += __shfl_xor(lr[r], 8);
    }

    // ---- merge 8 j-slice partials (plain sums; no max weighting needed) ----
#pragma unroll
    for (int rg = 0; rg < 2; ++rg) {
        __syncthreads();
        if (wi == rg) {
#pragma unroll
            for (int dt = 0; dt < 8; ++dt)
#pragma unroll
                for (int r = 0; r < 4; ++r)
                    Opart[(wj * 16 + g * 4 + r) * 128 + dt * 16 + ln] = acc[dt][r];
            if (ln == 0) {
#pragma unroll
                for (int r = 0; r < 4; ++r) Lpart[wj * 16 + g * 4 + r] = lr[r];
            }
        }
        __syncthreads();
        const int row = tid >> 6;          // 0..15
        const int c2  = (tid & 63) * 2;    // 0..126
        float L = 0.f;
#pragma unroll
        for (int p = 0; p < 8; ++p) L += Lpart[p * 16 + row];
        float o0 = 0.f, o1 = 0.f;
#pragma unroll
        for (int p = 0; p < 8; ++p) {
            const float* op = Opart + (p * 16 + row) * 128 + c2;
            o0 += op[0];
            o1 += op[1];
        }
        float inv = 1.0f / fmaxf(L, 1e-37f);
        float2 ov = {o0 * inv, o1 * inv};
        *(float2*)(out + (size_t)(i0 + rg * 16 + row) * DIM + c2) = ov;
    }
}

extern "C" void kernel_launch(void* const* d_in, const int* in_sizes, int n_in,
                              void* d_out, int out_size, void* d_ws, size_t ws_size,
                              hipStream_t stream) {
    const float* xi   = (const float*)d_in[0];
    const float* xj   = (const float*)d_in[1];
    const int*   adj  = (const int*)d_in[2];
    const float* beta = (const float*)d_in[3];
    float* out = (float*)d_out;

    char* ws = (char*)d_ws;
    __hip_bfloat16* Qbf = (__hip_bfloat16*)ws;                                   // 2 MiB
    __hip_bfloat16* Kbf = (__hip_bfloat16*)(ws + (size_t)NROWS * DIM * 2);       // 2 MiB
    __hip_bfloat16* Vt  = (__hip_bfloat16*)(ws + 2 * (size_t)NROWS * DIM * 2);   // 2 MiB

    hipLaunchKernelGGL(prep_scale_rows, dim3(2048), dim3(256), 0, stream, xi, beta, Qbf);
    hipLaunchKernelGGL(prep_scale_rows, dim3(2048), dim3(256), 0, stream, xj, (const float*)nullptr, Kbf);
    hipLaunchKernelGGL(prep_vt, dim3(128, 2), dim3(256), 0, stream, xj, Vt);
    hipLaunchKernelGGL(flash3, dim3(NROWS / BI), dim3(1024), 0, stream, Qbf, Kbf, Vt, adj, out);
}